// Round 1
// baseline (169112.793 us; speedup 1.0000x reference)
//
#include <hip/hip_runtime.h>
#include <cstdint>
#include <cstddef>

// ---------------------------------------------------------------------------
// 2-layer LSTM sampler, BATCH=2048 rows, 100 steps.
// Token sampling must reproduce jax.random.categorical bit-decisions:
//   keys = split(key(42), 100)   [foldlike: keys[t] = threefry((0,42),(0,t))]
//   bits(i) = b0 ^ b1 of threefry(keys[t], (0, i)), i = row*32 + v   [partitionable]
//   u = max(FLT_MIN, bitcast((bits>>9)|0x3f800000) - 1.0f)
//   g = -log(-log(u));  tok = argmax_v(logits[v] + g[v])  (first-max wins)
// All matmul/cell math accumulated in fp64; h/c stored fp32 (matches ref's f32
// state rounding), so our deviation vs the reference is ~the ref's own f32
// rounding only -> argmax flips are ~measure-zero.
// ---------------------------------------------------------------------------

constexpr int PAD_TOK = 0, BOS_TOK = 1, EOS_TOK = 2;
constexpr int VOCAB = 32, EMB = 64, HID = 1024, BATCH = 2048, MAXLEN = 100;

// GEMM tile: 32 rows x 32 h-units per block (x4 gates), K-chunk 64.
constexpr int TR = 32, TU = 32, KT = 64, LDSP = KT + 2;  // pad stride 66 floats

__device__ __forceinline__ uint32_t rotl32(uint32_t v, int d) {
  return (v << d) | (v >> (32 - d));
}

// Exact JAX threefry2x32 (5 groups of 4 rounds).
__device__ __forceinline__ void threefry2x32(uint32_t k0, uint32_t k1,
                                             uint32_t x0, uint32_t x1,
                                             uint32_t& y0, uint32_t& y1) {
  const uint32_t k2 = k0 ^ k1 ^ 0x1BD11BDAu;
#define TF_ROUND(r) do { x0 += x1; x1 = rotl32(x1, (r)); x1 ^= x0; } while (0)
  x0 += k0; x1 += k1;
  TF_ROUND(13); TF_ROUND(15); TF_ROUND(26); TF_ROUND(6);
  x0 += k1; x1 += k2 + 1u;
  TF_ROUND(17); TF_ROUND(29); TF_ROUND(16); TF_ROUND(24);
  x0 += k2; x1 += k0 + 2u;
  TF_ROUND(13); TF_ROUND(15); TF_ROUND(26); TF_ROUND(6);
  x0 += k0; x1 += k1 + 3u;
  TF_ROUND(17); TF_ROUND(29); TF_ROUND(16); TF_ROUND(24);
  x0 += k1; x1 += k2 + 4u;
  TF_ROUND(13); TF_ROUND(15); TF_ROUND(26); TF_ROUND(6);
  x0 += k2; x1 += k0 + 5u;
#undef TF_ROUND
  y0 = x0; y1 = x1;
}

// ---------------------------------------------------------------------------
// Init: zero states, seed prev/is_end/lengths, write sequences[:,0], compute
// the 100 step keys (foldlike split of key(42)).
// ---------------------------------------------------------------------------
__global__ __launch_bounds__(256) void init_kernel(
    const int* __restrict__ prevs,
    float* __restrict__ h0a, float* __restrict__ c0,
    float* __restrict__ h1a, float* __restrict__ c1,
    int* __restrict__ prev, int* __restrict__ is_end, int* __restrict__ lengths,
    uint32_t* __restrict__ keys, int* __restrict__ out_tok) {
  const int tid = blockIdx.x * blockDim.x + threadIdx.x;
  const int total = BATCH * HID;
  if (tid < total) {
    h0a[tid] = 0.0f; c0[tid] = 0.0f; h1a[tid] = 0.0f; c1[tid] = 0.0f;
  }
  if (tid < BATCH) {
    const int p = prevs[tid];
    prev[tid] = p;
    is_end[tid] = (p == EOS_TOK) ? 1 : 0;
    lengths[tid] = 0;
    out_tok[(size_t)tid * (MAXLEN + 1)] = p;
  }
  if (tid < MAXLEN) {
    uint32_t y0, y1;
    threefry2x32(0u, 42u, 0u, (uint32_t)tid, y0, y1);
    keys[2 * tid] = y0;
    keys[2 * tid + 1] = y1;
  }
}

// ---------------------------------------------------------------------------
// One LSTM layer for one step:
//   gates = X @ Wih^T + bih + Hin @ Whh^T + bhh  (fp64 acc)
//   c = sig(f)*c + sig(i)*tanh(g); h = sig(o)*tanh(c)   (fp64, stored fp32)
// GATHER: X rows come from emb[prev[row]] (K=64), else X is an [BATCH,HID]
// fp32 buffer (K=1024).
// Block: 256 threads = 16x16; thread owns 2 rows x 2 units x 4 gates.
// ---------------------------------------------------------------------------
template <bool GATHER>
__global__ __launch_bounds__(256) void lstm_layer(
    const float* __restrict__ Wih, int ldWih, int nxch,
    const float* __restrict__ Xsrc, const int* __restrict__ prevTok,
    const float* __restrict__ Whh,
    const float* __restrict__ Hin,
    const float* __restrict__ bih, const float* __restrict__ bhh,
    float* __restrict__ C, float* __restrict__ Hout) {
  __shared__ float Xs[TR][LDSP];
  __shared__ float Ws[4][TU][LDSP];
  __shared__ int ptok[TR];

  const int tid = threadIdx.x;
  const int tx = tid & 15, ty = tid >> 4;
  const int u0 = blockIdx.x * TU;
  const int row0 = blockIdx.y * TR;

  if (GATHER && tid < TR) ptok[tid] = prevTok[row0 + tid];

  double acc[2][2][4];
#pragma unroll
  for (int a = 0; a < 2; ++a)
#pragma unroll
    for (int b = 0; b < 2; ++b)
#pragma unroll
      for (int g = 0; g < 4; ++g) acc[a][b][g] = 0.0;

  for (int ph = 0; ph < 2; ++ph) {
    const float* W = ph ? Whh : Wih;
    const int ldw = ph ? HID : ldWih;
    const int nch = ph ? (HID / KT) : nxch;
    const float* X = ph ? Hin : Xsrc;
    const bool gat = GATHER && (ph == 0);

    for (int ch = 0; ch < nch; ++ch) {
      const int k0 = ch * KT;
      __syncthreads();  // protect LDS reuse (also orders ptok writes, ch==0)
      // stage X tile: TR rows x KT cols  (512 float4 slots, 2 per thread)
#pragma unroll 1
      for (int idx = tid; idx < TR * (KT / 4); idx += 256) {
        const int r = idx >> 4, ks = idx & 15;
        const float* src =
            gat ? (X + (size_t)ptok[r] * EMB + (k0 + ks * 4))
                : (X + (size_t)(row0 + r) * HID + (k0 + ks * 4));
        const float4 vv = *(const float4*)src;
        float2* d = (float2*)&Xs[r][ks * 4];
        d[0] = make_float2(vv.x, vv.y);
        d[1] = make_float2(vv.z, vv.w);
      }
      // stage W tile: 4 gates x TU rows x KT cols (2048 float4 slots, 8/thread)
#pragma unroll 1
      for (int idx = tid; idx < 4 * TU * (KT / 4); idx += 256) {
        const int ks = idx & 15;
        const int rr = idx >> 4;  // 0..127
        const int g = rr >> 5, ui = rr & 31;
        const float4 vv = *(const float4*)(W + (size_t)(g * HID + u0 + ui) * ldw +
                                           (k0 + ks * 4));
        float2* d = (float2*)&Ws[g][ui][ks * 4];
        d[0] = make_float2(vv.x, vv.y);
        d[1] = make_float2(vv.z, vv.w);
      }
      __syncthreads();

#pragma unroll 4
      for (int kk = 0; kk < KT; kk += 2) {
        const float2 xa = *(const float2*)&Xs[ty][kk];
        const float2 xb = *(const float2*)&Xs[ty + 16][kk];
        const double xa0 = (double)xa.x, xa1 = (double)xa.y;
        const double xb0 = (double)xb.x, xb1 = (double)xb.y;
#pragma unroll
        for (int g = 0; g < 4; ++g) {
          const float2 wa = *(const float2*)&Ws[g][tx][kk];
          const float2 wb = *(const float2*)&Ws[g][tx + 16][kk];
          const double wa0 = (double)wa.x, wa1 = (double)wa.y;
          const double wb0 = (double)wb.x, wb1 = (double)wb.y;
          acc[0][0][g] = fma(xa1, wa1, fma(xa0, wa0, acc[0][0][g]));
          acc[0][1][g] = fma(xa1, wb1, fma(xa0, wb0, acc[0][1][g]));
          acc[1][0][g] = fma(xb1, wa1, fma(xb0, wa0, acc[1][0][g]));
          acc[1][1][g] = fma(xb1, wb1, fma(xb0, wb0, acc[1][1][g]));
        }
      }
    }
  }

  // epilogue: bias + cell update (fp64, store fp32)
#pragma unroll
  for (int ri = 0; ri < 2; ++ri) {
    const int r = row0 + ty + ri * 16;
#pragma unroll
    for (int uj = 0; uj < 2; ++uj) {
      const int u = u0 + tx + uj * 16;
      const double gi = acc[ri][uj][0] + (double)bih[u] + (double)bhh[u];
      const double gf =
          acc[ri][uj][1] + (double)bih[HID + u] + (double)bhh[HID + u];
      const double gg =
          acc[ri][uj][2] + (double)bih[2 * HID + u] + (double)bhh[2 * HID + u];
      const double go =
          acc[ri][uj][3] + (double)bih[3 * HID + u] + (double)bhh[3 * HID + u];
      const double ii = 1.0 / (1.0 + exp(-gi));
      const double ff = 1.0 / (1.0 + exp(-gf));
      const double gt = tanh(gg);
      const double oo = 1.0 / (1.0 + exp(-go));
      const size_t off = (size_t)r * HID + u;
      const double cn = ff * (double)C[off] + ii * gt;
      C[off] = (float)cn;
      Hout[off] = (float)(oo * tanh(cn));
    }
  }
}

// ---------------------------------------------------------------------------
// Logits + gumbel + argmax + EOS bookkeeping. One wave per row (4 rows/block).
// Lane v (= lane&31) owns vocab entry v; halves (lane>>5) split K.
// ---------------------------------------------------------------------------
__global__ __launch_bounds__(256) void sample_kernel(
    const float* __restrict__ h1, const float* __restrict__ Wout,
    const float* __restrict__ bout, const uint32_t* __restrict__ keys, int t,
    int* __restrict__ prev, int* __restrict__ is_end, int* __restrict__ lengths,
    int* __restrict__ out_tok, int* __restrict__ len_out) {
  const int wave = threadIdx.x >> 6;
  const int lane = threadIdx.x & 63;
  const int row = blockIdx.x * 4 + wave;
  const int v = lane & 31;
  const int half = lane >> 5;

  const float* hseg = h1 + (size_t)row * HID + half * (HID / 2);
  const float* wseg = Wout + (size_t)v * HID + half * (HID / 2);

  double acc = 0.0;
#pragma unroll 4
  for (int k = 0; k < HID / 2; k += 4) {
    const float4 w = *(const float4*)(wseg + k);
    const float4 h = *(const float4*)(hseg + k);
    acc = fma((double)w.x, (double)h.x, acc);
    acc = fma((double)w.y, (double)h.y, acc);
    acc = fma((double)w.z, (double)h.z, acc);
    acc = fma((double)w.w, (double)h.w, acc);
  }
  acc += __shfl_xor(acc, 32);  // combine K-halves; both halves now hold full dot

  // gumbel(row, v) with JAX partitionable threefry bits
  const uint32_t k0 = keys[2 * t], k1 = keys[2 * t + 1];
  uint32_t y0, y1;
  threefry2x32(k0, k1, 0u, (uint32_t)(row * VOCAB + v), y0, y1);
  const uint32_t bits = y0 ^ y1;
  const float f = __uint_as_float((bits >> 9) | 0x3f800000u) - 1.0f;
  const float u = fmaxf(f, 1.17549435e-38f);
  const double g = -log(-log((double)u));

  double z = acc + (double)bout[v] + g;
  int idx = v;
#pragma unroll
  for (int m = 1; m < 32; m <<= 1) {
    const double zo = __shfl_xor(z, m);
    const int io = __shfl_xor(idx, m);
    if (zo > z || (zo == z && io < idx)) { z = zo; idx = io; }
  }

  if (lane == 0) {
    const int e = is_end[row];
    const int cur = e ? PAD_TOK : idx;
    const int len = lengths[row] + (e ? 0 : 1);
    const int enew = e | (cur == EOS_TOK ? 1 : 0);
    prev[row] = cur;
    is_end[row] = enew;
    lengths[row] = len;
    out_tok[(size_t)row * (MAXLEN + 1) + t + 1] = cur;
    if (len_out) len_out[row] = len + 1;  // reference returns lengths+1 (BOS)
  }
}

// ---------------------------------------------------------------------------
extern "C" void kernel_launch(void* const* d_in, const int* in_sizes, int n_in,
                              void* d_out, int out_size, void* d_ws,
                              size_t ws_size, hipStream_t stream) {
  const int* prevs = (const int*)d_in[0];
  const float* emb = (const float*)d_in[1];
  const float* Wih0 = (const float*)d_in[2];
  const float* Whh0 = (const float*)d_in[3];
  const float* bih0 = (const float*)d_in[4];
  const float* bhh0 = (const float*)d_in[5];
  const float* Wih1 = (const float*)d_in[6];
  const float* Whh1 = (const float*)d_in[7];
  const float* bih1 = (const float*)d_in[8];
  const float* bhh1 = (const float*)d_in[9];
  const float* Wout = (const float*)d_in[10];
  const float* bout = (const float*)d_in[11];

  const size_t SH = (size_t)BATCH * HID;
  float* h0a = (float*)d_ws;
  float* h0b = h0a + SH;
  float* c0 = h0b + SH;
  float* h1a = c0 + SH;
  float* h1b = h1a + SH;
  float* c1 = h1b + SH;
  int* prev = (int*)(c1 + SH);
  int* is_end = prev + BATCH;
  int* lengths = is_end + BATCH;
  uint32_t* keys = (uint32_t*)(lengths + BATCH);
  // ws usage: 6*8MB + ~24KB ≈ 50.4 MB

  int* out_tok = (int*)d_out;
  int* len_out = out_tok + (size_t)BATCH * (MAXLEN + 1);

  init_kernel<<<dim3((BATCH * HID) / 256), 256, 0, stream>>>(
      prevs, h0a, c0, h1a, c1, prev, is_end, lengths, keys, out_tok);

  dim3 lgrid(HID / TU, BATCH / TR);  // (32, 64)
  float *h0i = h0a, *h0o = h0b, *h1i = h1a, *h1o = h1b;
  for (int t = 0; t < MAXLEN; ++t) {
    lstm_layer<true><<<lgrid, 256, 0, stream>>>(
        Wih0, EMB, 1, emb, prev, Whh0, h0i, bih0, bhh0, c0, h0o);
    lstm_layer<false><<<lgrid, 256, 0, stream>>>(
        Wih1, HID, HID / KT, h0o, nullptr, Whh1, h1i, bih1, bhh1, c1, h1o);
    sample_kernel<<<dim3(BATCH / 4), 256, 0, stream>>>(
        h1o, Wout, bout, keys, t, prev, is_end, lengths, out_tok,
        (t == MAXLEN - 1) ? len_out : nullptr);
    float* tmp = h0i; h0i = h0o; h0o = tmp;
    tmp = h1i; h1i = h1o; h1o = tmp;
  }
  (void)in_sizes; (void)n_in; (void)out_size; (void)ws_size;
}

// Round 2
// 56662.305 us; speedup vs baseline: 2.9846x; 2.9846x over previous
//
#include <hip/hip_runtime.h>
#include <cstdint>
#include <cstddef>

// ---------------------------------------------------------------------------
// 2-layer LSTM sampler, BATCH=2048, 100 steps, exact jax.random.categorical
// reproduction (threefry2x32, partitionable bits). Round-2: LSTM GEMMs on
// matrix cores via fp16x3 split (hi/lo, x64 scaled); epilogue + sampler fp64.
// ---------------------------------------------------------------------------

constexpr int PAD_TOK = 0, BOS_TOK = 1, EOS_TOK = 2;
constexpr int VOCAB = 32, EMB = 64, HID = 1024, BATCH = 2048, MAXLEN = 100;
constexpr int BM = 128, BK = 32;      // N-tile = 128 = 4 gates x 32 units
constexpr float SCALE = 64.0f;        // fp16-split scale (keeps lo normal)
constexpr double INV_S2 = 1.0 / 4096.0;

using half8 = __attribute__((ext_vector_type(8))) _Float16;
using f32x4 = __attribute__((ext_vector_type(4))) float;
typedef unsigned short u16;
typedef uint32_t u32;

__device__ __forceinline__ u32 rotl32(u32 v, int d) {
  return (v << d) | (v >> (32 - d));
}

__device__ __forceinline__ void threefry2x32(u32 k0, u32 k1, u32 x0, u32 x1,
                                             u32& y0, u32& y1) {
  const u32 k2 = k0 ^ k1 ^ 0x1BD11BDAu;
#define TF_ROUND(r) do { x0 += x1; x1 = rotl32(x1, (r)); x1 ^= x0; } while (0)
  x0 += k0; x1 += k1;
  TF_ROUND(13); TF_ROUND(15); TF_ROUND(26); TF_ROUND(6);
  x0 += k1; x1 += k2 + 1u;
  TF_ROUND(17); TF_ROUND(29); TF_ROUND(16); TF_ROUND(24);
  x0 += k2; x1 += k0 + 2u;
  TF_ROUND(13); TF_ROUND(15); TF_ROUND(26); TF_ROUND(6);
  x0 += k0; x1 += k1 + 3u;
  TF_ROUND(17); TF_ROUND(29); TF_ROUND(16); TF_ROUND(24);
  x0 += k1; x1 += k2 + 4u;
  TF_ROUND(13); TF_ROUND(15); TF_ROUND(26); TF_ROUND(6);
  x0 += k2; x1 += k0 + 5u;
#undef TF_ROUND
  y0 = x0; y1 = x1;
}

// ---------------------------------------------------------------------------
// fp16 hi/lo split of a f32 array, scaled by 64.
// ---------------------------------------------------------------------------
__global__ __launch_bounds__(256) void split_kernel(
    const float* __restrict__ src, u16* __restrict__ hi, u16* __restrict__ lo,
    int n) {
  const int i = blockIdx.x * 256 + threadIdx.x;
  if (i >= n) return;
  const float x = src[i] * SCALE;
  const _Float16 h = (_Float16)x;
  const float rem = x - (float)h;
  const _Float16 l = (_Float16)rem;
  hi[i] = __builtin_bit_cast(u16, h);
  lo[i] = __builtin_bit_cast(u16, l);
}

// ---------------------------------------------------------------------------
// Init: zero c-states and h split planes, seed prev/is_end/lengths, BOS col,
// step keys.
// ---------------------------------------------------------------------------
__global__ __launch_bounds__(256) void init_kernel(
    const int* __restrict__ prevs, float* __restrict__ c0,
    float* __restrict__ c1, u16* __restrict__ h0hi0, u16* __restrict__ h0lo0,
    u16* __restrict__ h0hi1, u16* __restrict__ h0lo1,
    u16* __restrict__ h1hi0, u16* __restrict__ h1lo0,
    u16* __restrict__ h1hi1, u16* __restrict__ h1lo1,
    int* __restrict__ prev, int* __restrict__ is_end,
    int* __restrict__ lengths, u32* __restrict__ keys,
    int* __restrict__ out_tok) {
  const int tid = blockIdx.x * 256 + threadIdx.x;
  const int total = BATCH * HID;
  if (tid < total) {
    c0[tid] = 0.0f; c1[tid] = 0.0f;
    h0hi0[tid] = 0; h0lo0[tid] = 0; h0hi1[tid] = 0; h0lo1[tid] = 0;
    h1hi0[tid] = 0; h1lo0[tid] = 0; h1hi1[tid] = 0; h1lo1[tid] = 0;
  }
  if (tid < BATCH) {
    const int p = prevs[tid];
    prev[tid] = p;
    is_end[tid] = (p == EOS_TOK) ? 1 : 0;
    lengths[tid] = 0;
    out_tok[(size_t)tid * (MAXLEN + 1)] = p;
  }
  if (tid < MAXLEN) {
    u32 y0, y1;
    threefry2x32(0u, 42u, 0u, (u32)tid, y0, y1);
    keys[2 * tid] = y0;
    keys[2 * tid + 1] = y1;
  }
}

// ---------------------------------------------------------------------------
// MFMA LSTM layer.  gates[2048,4096] = A0*W0^T + A1*W1^T (fp16x3 split, x64
// scaled both sides) then fused fp64 cell update.
// Block: 128 rows x (4 gates x 32 units); 4 waves (2x2); 16x16x32 f16 MFMA.
// LDS: fragment-ordered tiles (slot = fm*64 + kgrp*16 + r15), so every
// ds_read_b128 is lane-consecutive (conflict-free); reg-staged double buffer.
// ---------------------------------------------------------------------------
template <bool GATHER, bool WRITE_F32>
__global__ __launch_bounds__(256, 2) void lstm_mfma(
    const u16* __restrict__ A0hi, const u16* __restrict__ A0lo, int lda0,
    int nk0, const int* __restrict__ ptok, const u16* __restrict__ A1hi,
    const u16* __restrict__ A1lo, const u16* __restrict__ W0hi,
    const u16* __restrict__ W0lo, const u16* __restrict__ W1hi,
    const u16* __restrict__ W1lo, const float* __restrict__ bih,
    const float* __restrict__ bhh, float* __restrict__ Cst,
    float* __restrict__ Hf32, u16* __restrict__ Hhi, u16* __restrict__ Hlo) {
  __shared__ uint4 lds4[4224];  // 67584 B: 2 x 32KB stage bufs, or 128x132 f32
  char* lds = (char*)lds4;

  const int tid = threadIdx.x;
  const int lane = tid & 63;
  const int wid = tid >> 6;
  const int wm = wid >> 1, wn = wid & 1;

  // XCD swizzle: 512 blocks, 64 logical per XCD -> same-W blocks share L2.
  const int bid = blockIdx.x;
  const int swz = (bid & 7) * 64 + (bid >> 3);
  const int ut = swz >> 4;   // 0..31 unit tile
  const int mt = swz & 15;   // 0..15 row tile
  const int u0 = ut * 32;
  const int row0 = mt * BM;

  // staging slot decode (2 slots per plane per thread: s = tid, tid+256)
  const int r15 = tid & 15;
  const int kgrp = (tid >> 4) & 3;
  const int fm0 = tid >> 6;
  int arow[2], wrow[2], tok[2];
  arow[0] = row0 + fm0 * 16 + r15;
  arow[1] = row0 + (fm0 + 4) * 16 + r15;
  if (GATHER) { tok[0] = ptok[arow[0]]; tok[1] = ptok[arow[1]]; }
  {
    int n = fm0 * 16 + r15;
    wrow[0] = (n >> 5) * HID + u0 + (n & 31);
    n = (fm0 + 4) * 16 + r15;
    wrow[1] = (n >> 5) * HID + u0 + (n & 31);
  }

  const int nk1 = HID / BK;
  const int NT = nk0 + nk1;

  auto ldso = [&](int buf, int plane, int slot) -> char* {
    return lds + buf * 32768 + plane * 8192 + slot * 16;
  };

  uint4 R[8];
  auto load_tile = [&](int kt) {
    const bool s0 = kt < nk0;
    const int kk = (s0 ? kt : kt - nk0) * BK;
    const u16* ah = s0 ? A0hi : A1hi;
    const u16* al = s0 ? A0lo : A1lo;
    const u16* wh = s0 ? W0hi : W1hi;
    const u16* wl = s0 ? W0lo : W1lo;
    const int lda = s0 ? lda0 : HID;
    const int kof = kk + kgrp * 8;
#pragma unroll
    for (int i = 0; i < 2; ++i) {
      const size_t aoff = (GATHER && s0)
                              ? ((size_t)tok[i] * lda + kof)
                              : ((size_t)arow[i] * lda + kof);
      R[0 + i] = *(const uint4*)(ah + aoff);
      R[2 + i] = *(const uint4*)(al + aoff);
      const size_t woff = (size_t)wrow[i] * lda + kof;
      R[4 + i] = *(const uint4*)(wh + woff);
      R[6 + i] = *(const uint4*)(wl + woff);
    }
  };
  auto write_tile = [&](int buf) {
#pragma unroll
    for (int p = 0; p < 4; ++p)
#pragma unroll
      for (int i = 0; i < 2; ++i)
        *(uint4*)ldso(buf, p, tid + i * 256) = R[p * 2 + i];
  };

  f32x4 acc[4][4] = {};

  auto compute = [&](int buf) {
    half8 ah[4], al[4];
#pragma unroll
    for (int mi = 0; mi < 4; ++mi) {
      ah[mi] = *(const half8*)ldso(buf, 0, (wm * 4 + mi) * 64 + lane);
      al[mi] = *(const half8*)ldso(buf, 1, (wm * 4 + mi) * 64 + lane);
    }
#pragma unroll
    for (int ni = 0; ni < 4; ++ni) {
      const half8 bh = *(const half8*)ldso(buf, 2, (wn * 4 + ni) * 64 + lane);
      const half8 bl = *(const half8*)ldso(buf, 3, (wn * 4 + ni) * 64 + lane);
#pragma unroll
      for (int mi = 0; mi < 4; ++mi) {
        acc[mi][ni] =
            __builtin_amdgcn_mfma_f32_16x16x32_f16(ah[mi], bh, acc[mi][ni], 0, 0, 0);
        acc[mi][ni] =
            __builtin_amdgcn_mfma_f32_16x16x32_f16(ah[mi], bl, acc[mi][ni], 0, 0, 0);
        acc[mi][ni] =
            __builtin_amdgcn_mfma_f32_16x16x32_f16(al[mi], bh, acc[mi][ni], 0, 0, 0);
      }
    }
  };

  load_tile(0);
  write_tile(0);
  __syncthreads();
#pragma unroll 1
  for (int t = 0; t < NT; ++t) {
    if (t + 1 < NT) load_tile(t + 1);   // async global loads, hide under MFMA
    compute(t & 1);
    if (t + 1 < NT) write_tile((t + 1) & 1);  // vmcnt waits inserted here
    __syncthreads();
  }

  // ---- epilogue: exchange C through LDS, fp64 cell update ----
  float* cb = (float*)lds;  // [128][132]
#pragma unroll
  for (int mi = 0; mi < 4; ++mi)
#pragma unroll
    for (int ni = 0; ni < 4; ++ni) {
      const int col = wn * 64 + ni * 16 + (lane & 15);
      const int rb = wm * 64 + mi * 16 + ((lane >> 4) << 2);
#pragma unroll
      for (int r = 0; r < 4; ++r) cb[(rb + r) * 132 + col] = acc[mi][ni][r];
    }
  __syncthreads();

#pragma unroll 1
  for (int i = 0; i < 16; ++i) {
    const int idx = tid + i * 256;
    const int r = idx >> 5, ui = idx & 31;
    const int grow = row0 + r;
    const int u = u0 + ui;
    const float* cr = cb + r * 132 + ui;
    const double gI = (double)cr[0]  * INV_S2 + (double)bih[u]           + (double)bhh[u];
    const double gF = (double)cr[32] * INV_S2 + (double)bih[HID + u]     + (double)bhh[HID + u];
    const double gG = (double)cr[64] * INV_S2 + (double)bih[2 * HID + u] + (double)bhh[2 * HID + u];
    const double gO = (double)cr[96] * INV_S2 + (double)bih[3 * HID + u] + (double)bhh[3 * HID + u];
    const double ii = 1.0 / (1.0 + exp(-gI));
    const double ff = 1.0 / (1.0 + exp(-gF));
    const double gt = tanh(gG);
    const double oo = 1.0 / (1.0 + exp(-gO));
    const size_t off = (size_t)grow * HID + u;
    const double cn = ff * (double)Cst[off] + ii * gt;
    Cst[off] = (float)cn;
    const float hf = (float)(oo * tanh(cn));
    if (WRITE_F32) Hf32[off] = hf;
    const float hs = hf * SCALE;
    const _Float16 hh = (_Float16)hs;
    const float rem = hs - (float)hh;
    const _Float16 hl = (_Float16)rem;
    Hhi[off] = __builtin_bit_cast(u16, hh);
    Hlo[off] = __builtin_bit_cast(u16, hl);
  }
}

// ---------------------------------------------------------------------------
// Logits + gumbel + argmax + EOS bookkeeping (fp64, unchanged from round 1).
// ---------------------------------------------------------------------------
__global__ __launch_bounds__(256) void sample_kernel(
    const float* __restrict__ h1, const float* __restrict__ Wout,
    const float* __restrict__ bout, const u32* __restrict__ keys, int t,
    int* __restrict__ prev, int* __restrict__ is_end, int* __restrict__ lengths,
    int* __restrict__ out_tok, int* __restrict__ len_out) {
  const int wave = threadIdx.x >> 6;
  const int lane = threadIdx.x & 63;
  const int row = blockIdx.x * 4 + wave;
  const int v = lane & 31;
  const int half = lane >> 5;

  const float* hseg = h1 + (size_t)row * HID + half * (HID / 2);
  const float* wseg = Wout + (size_t)v * HID + half * (HID / 2);

  double acc = 0.0;
#pragma unroll 4
  for (int k = 0; k < HID / 2; k += 4) {
    const float4 w = *(const float4*)(wseg + k);
    const float4 h = *(const float4*)(hseg + k);
    acc = fma((double)w.x, (double)h.x, acc);
    acc = fma((double)w.y, (double)h.y, acc);
    acc = fma((double)w.z, (double)h.z, acc);
    acc = fma((double)w.w, (double)h.w, acc);
  }
  acc += __shfl_xor(acc, 32);

  const u32 k0 = keys[2 * t], k1 = keys[2 * t + 1];
  u32 y0, y1;
  threefry2x32(k0, k1, 0u, (u32)(row * VOCAB + v), y0, y1);
  const u32 bits = y0 ^ y1;
  const float f = __uint_as_float((bits >> 9) | 0x3f800000u) - 1.0f;
  const float uu = fmaxf(f, 1.17549435e-38f);
  const double g = -log(-log((double)uu));

  double z = acc + (double)bout[v] + g;
  int idx = v;
#pragma unroll
  for (int m = 1; m < 32; m <<= 1) {
    const double zo = __shfl_xor(z, m);
    const int io = __shfl_xor(idx, m);
    if (zo > z || (zo == z && io < idx)) { z = zo; idx = io; }
  }

  if (lane == 0) {
    const int e = is_end[row];
    const int cur = e ? PAD_TOK : idx;
    const int len = lengths[row] + (e ? 0 : 1);
    const int enew = e | (cur == EOS_TOK ? 1 : 0);
    prev[row] = cur;
    is_end[row] = enew;
    lengths[row] = len;
    out_tok[(size_t)row * (MAXLEN + 1) + t + 1] = cur;
    if (len_out) len_out[row] = len + 1;
  }
}

// ---------------------------------------------------------------------------
extern "C" void kernel_launch(void* const* d_in, const int* in_sizes, int n_in,
                              void* d_out, int out_size, void* d_ws,
                              size_t ws_size, hipStream_t stream) {
  const int* prevs = (const int*)d_in[0];
  const float* emb = (const float*)d_in[1];
  const float* Wih0 = (const float*)d_in[2];
  const float* Whh0 = (const float*)d_in[3];
  const float* bih0 = (const float*)d_in[4];
  const float* bhh0 = (const float*)d_in[5];
  const float* Wih1 = (const float*)d_in[6];
  const float* Whh1 = (const float*)d_in[7];
  const float* bih1 = (const float*)d_in[8];
  const float* bhh1 = (const float*)d_in[9];
  const float* Wout = (const float*)d_in[10];
  const float* bout = (const float*)d_in[11];

  const size_t SH = (size_t)BATCH * HID;        // 2M elements
  const size_t SW = (size_t)(4 * HID) * HID;    // 4M elements
  const size_t SW0 = (size_t)(4 * HID) * EMB;   // 256K elements

  float* c0 = (float*)d_ws;
  float* c1 = c0 + SH;
  float* h1f = c1 + SH;
  u16* u = (u16*)(h1f + SH);
  u16* h0hi[2] = {u, u + SH};
  u16* h0lo[2] = {u + 2 * SH, u + 3 * SH};
  u16* h1hi[2] = {u + 4 * SH, u + 5 * SH};
  u16* h1lo[2] = {u + 6 * SH, u + 7 * SH};
  u16* wp = u + 8 * SH;
  u16* wih0hi = wp;            u16* wih0lo = wp + SW0;
  u16* whh0hi = wp + 2 * SW0;  u16* whh0lo = whh0hi + SW;
  u16* wih1hi = whh0lo + SW;   u16* wih1lo = wih1hi + SW;
  u16* whh1hi = wih1lo + SW;   u16* whh1lo = whh1hi + SW;
  u16* embhi = whh1lo + SW;    u16* emblo = embhi + VOCAB * EMB;
  int* prev = (int*)(emblo + VOCAB * EMB);
  int* is_end = prev + BATCH;
  int* lengths = is_end + BATCH;
  u32* keys = (u32*)(lengths + BATCH);
  // total ~106 MB

  int* out_tok = (int*)d_out;
  int* len_out = out_tok + (size_t)BATCH * (MAXLEN + 1);

  init_kernel<<<dim3((BATCH * HID) / 256), 256, 0, stream>>>(
      prevs, c0, c1, h0hi[0], h0lo[0], h0hi[1], h0lo[1], h1hi[0], h1lo[0],
      h1hi[1], h1lo[1], prev, is_end, lengths, keys, out_tok);

  split_kernel<<<dim3((int)((SW0 + 255) / 256)), 256, 0, stream>>>(Wih0, wih0hi, wih0lo, (int)SW0);
  split_kernel<<<dim3((int)((SW + 255) / 256)), 256, 0, stream>>>(Whh0, whh0hi, whh0lo, (int)SW);
  split_kernel<<<dim3((int)((SW + 255) / 256)), 256, 0, stream>>>(Wih1, wih1hi, wih1lo, (int)SW);
  split_kernel<<<dim3((int)((SW + 255) / 256)), 256, 0, stream>>>(Whh1, whh1hi, whh1lo, (int)SW);
  split_kernel<<<dim3((VOCAB * EMB + 255) / 256), 256, 0, stream>>>(emb, embhi, emblo, VOCAB * EMB);

  int p = 0;
  for (int t = 0; t < MAXLEN; ++t) {
    lstm_mfma<true, false><<<dim3(512), 256, 0, stream>>>(
        embhi, emblo, EMB, EMB / BK, prev, h0hi[p], h0lo[p], wih0hi, wih0lo,
        whh0hi, whh0lo, bih0, bhh0, c0, nullptr, h0hi[p ^ 1], h0lo[p ^ 1]);
    lstm_mfma<false, true><<<dim3(512), 256, 0, stream>>>(
        h0hi[p ^ 1], h0lo[p ^ 1], HID, HID / BK, nullptr, h1hi[p], h1lo[p],
        wih1hi, wih1lo, whh1hi, whh1lo, bih1, bhh1, c1, h1f, h1hi[p ^ 1],
        h1lo[p ^ 1]);
    sample_kernel<<<dim3(BATCH / 4), 256, 0, stream>>>(
        h1f, Wout, bout, keys, t, prev, is_end, lengths, out_tok,
        (t == MAXLEN - 1) ? len_out : nullptr);
    p ^= 1;
  }
  (void)in_sizes; (void)n_in; (void)out_size; (void)ws_size;
}

// Round 3
// 27220.660 us; speedup vs baseline: 6.2127x; 2.0816x over previous
//
#include <hip/hip_runtime.h>
#include <cstdint>
#include <cstddef>

// ---------------------------------------------------------------------------
// 2-layer LSTM sampler, BATCH=2048, 100 steps, exact jax.random.categorical
// reproduction (threefry2x32, partitionable bits). Round-3: same fp16x3 MFMA
// math as round 2 (proven absmax 0.0), but staging via global_load_lds
// (width 16) instead of register round-trip -> no VGPR spills, fewer LDS
// writes, loads overlap MFMA (m97 structure).
// ---------------------------------------------------------------------------

constexpr int PAD_TOK = 0, BOS_TOK = 1, EOS_TOK = 2;
constexpr int VOCAB = 32, EMB = 64, HID = 1024, BATCH = 2048, MAXLEN = 100;
constexpr int BM = 128, BK = 32;      // N-tile = 128 = 4 gates x 32 units
constexpr float SCALE = 64.0f;        // fp16-split scale (keeps lo normal)
constexpr double INV_S2 = 1.0 / 4096.0;

using half8 = __attribute__((ext_vector_type(8))) _Float16;
using f32x4 = __attribute__((ext_vector_type(4))) float;
typedef unsigned short u16;
typedef uint32_t u32;

__device__ __forceinline__ u32 rotl32(u32 v, int d) {
  return (v << d) | (v >> (32 - d));
}

__device__ __forceinline__ void threefry2x32(u32 k0, u32 k1, u32 x0, u32 x1,
                                             u32& y0, u32& y1) {
  const u32 k2 = k0 ^ k1 ^ 0x1BD11BDAu;
#define TF_ROUND(r) do { x0 += x1; x1 = rotl32(x1, (r)); x1 ^= x0; } while (0)
  x0 += k0; x1 += k1;
  TF_ROUND(13); TF_ROUND(15); TF_ROUND(26); TF_ROUND(6);
  x0 += k1; x1 += k2 + 1u;
  TF_ROUND(17); TF_ROUND(29); TF_ROUND(16); TF_ROUND(24);
  x0 += k2; x1 += k0 + 2u;
  TF_ROUND(13); TF_ROUND(15); TF_ROUND(26); TF_ROUND(6);
  x0 += k0; x1 += k1 + 3u;
  TF_ROUND(17); TF_ROUND(29); TF_ROUND(16); TF_ROUND(24);
  x0 += k1; x1 += k2 + 4u;
  TF_ROUND(13); TF_ROUND(15); TF_ROUND(26); TF_ROUND(6);
  x0 += k2; x1 += k0 + 5u;
#undef TF_ROUND
  y0 = x0; y1 = x1;
}

// async global->LDS, 16 bytes per lane; LDS dest must be wave-uniform base.
__device__ __forceinline__ void gl_lds16(const void* g, void* l) {
  __builtin_amdgcn_global_load_lds(
      (const __attribute__((address_space(1))) void*)g,
      (__attribute__((address_space(3))) void*)l, 16, 0, 0);
}

// ---------------------------------------------------------------------------
// fp16 hi/lo split of a f32 array, scaled by 64.
// ---------------------------------------------------------------------------
__global__ __launch_bounds__(256) void split_kernel(
    const float* __restrict__ src, u16* __restrict__ hi, u16* __restrict__ lo,
    int n) {
  const int i = blockIdx.x * 256 + threadIdx.x;
  if (i >= n) return;
  const float x = src[i] * SCALE;
  const _Float16 h = (_Float16)x;
  const float rem = x - (float)h;
  const _Float16 l = (_Float16)rem;
  hi[i] = __builtin_bit_cast(u16, h);
  lo[i] = __builtin_bit_cast(u16, l);
}

// ---------------------------------------------------------------------------
__global__ __launch_bounds__(256) void init_kernel(
    const int* __restrict__ prevs, float* __restrict__ c0,
    float* __restrict__ c1, u16* __restrict__ h0hi0, u16* __restrict__ h0lo0,
    u16* __restrict__ h0hi1, u16* __restrict__ h0lo1,
    u16* __restrict__ h1hi0, u16* __restrict__ h1lo0,
    u16* __restrict__ h1hi1, u16* __restrict__ h1lo1,
    int* __restrict__ prev, int* __restrict__ is_end,
    int* __restrict__ lengths, u32* __restrict__ keys,
    int* __restrict__ out_tok) {
  const int tid = blockIdx.x * 256 + threadIdx.x;
  const int total = BATCH * HID;
  if (tid < total) {
    c0[tid] = 0.0f; c1[tid] = 0.0f;
    h0hi0[tid] = 0; h0lo0[tid] = 0; h0hi1[tid] = 0; h0lo1[tid] = 0;
    h1hi0[tid] = 0; h1lo0[tid] = 0; h1hi1[tid] = 0; h1lo1[tid] = 0;
  }
  if (tid < BATCH) {
    const int p = prevs[tid];
    prev[tid] = p;
    is_end[tid] = (p == EOS_TOK) ? 1 : 0;
    lengths[tid] = 0;
    out_tok[(size_t)tid * (MAXLEN + 1)] = p;
  }
  if (tid < MAXLEN) {
    u32 y0, y1;
    threefry2x32(0u, 42u, 0u, (u32)tid, y0, y1);
    keys[2 * tid] = y0;
    keys[2 * tid + 1] = y1;
  }
}

// ---------------------------------------------------------------------------
// MFMA LSTM layer.  gates[2048,4096] = A0*W0^T + A1*W1^T (fp16x3 split, x64
// scaled both sides) then fused fp64 cell update.
// Block: 128 rows x (4 gates x 32 units); 4 waves (2x2); 16x16x32 f16 MFMA.
// LDS: fragment-ordered tiles (slot = fm*64 + kgrp*16 + r15) so every
// ds_read_b128 is lane-consecutive; staging via global_load_lds width=16
// (wave-uniform LDS base + lane*16 == slot layout by construction).
// ---------------------------------------------------------------------------
template <bool GATHER, bool WRITE_F32>
__global__ __launch_bounds__(256) void lstm_mfma(
    const u16* __restrict__ A0hi, const u16* __restrict__ A0lo, int lda0,
    int nk0, const int* __restrict__ ptok, const u16* __restrict__ A1hi,
    const u16* __restrict__ A1lo, const u16* __restrict__ W0hi,
    const u16* __restrict__ W0lo, const u16* __restrict__ W1hi,
    const u16* __restrict__ W1lo, const float* __restrict__ bih,
    const float* __restrict__ bhh, float* __restrict__ Cst,
    float* __restrict__ Hf32, u16* __restrict__ Hhi, u16* __restrict__ Hlo) {
  __shared__ uint4 lds4[4224];  // 67584 B: 2 x 32KB stage bufs, or 128x132 f32
  char* lds = (char*)lds4;

  const int tid = threadIdx.x;
  const int lane = tid & 63;
  const int wid = tid >> 6;
  const int wm = wid >> 1, wn = wid & 1;

  // XCD swizzle: 512 blocks, 64 logical per XCD -> same-W blocks share L2.
  const int bid = blockIdx.x;
  const int swz = (bid & 7) * 64 + (bid >> 3);
  const int ut = swz >> 4;   // 0..31 unit tile
  const int mt = swz & 15;   // 0..15 row tile
  const int u0 = ut * 32;
  const int row0 = mt * BM;

  // staging decode: slot = wid*64 + i*256 + lane  (identical map to round 2)
  const int r15 = lane & 15;
  const int kgrp = lane >> 4;  // 0..3
  int arow[2], wrow[2], tok[2];
#pragma unroll
  for (int i = 0; i < 2; ++i) {
    const int fm = wid + i * 4;
    arow[i] = row0 + fm * 16 + r15;
    const int n = fm * 16 + r15;
    wrow[i] = (n >> 5) * HID + u0 + (n & 31);
  }
  if (GATHER) { tok[0] = ptok[arow[0]]; tok[1] = ptok[arow[1]]; }

  const int nk1 = HID / BK;
  const int NT = nk0 + nk1;

  auto ldso = [&](int buf, int plane, int slot) -> char* {
    return lds + buf * 32768 + plane * 8192 + slot * 16;
  };

  // issue 8 global_load_lds (4 planes x 2 row-groups) for k-tile kt into buf
  auto stage = [&](int buf, int kt) {
    const bool s0 = kt < nk0;
    const int kk = (s0 ? kt : kt - nk0) * BK;
    const u16* ah = s0 ? A0hi : A1hi;
    const u16* al = s0 ? A0lo : A1lo;
    const u16* wh = s0 ? W0hi : W1hi;
    const u16* wl = s0 ? W0lo : W1lo;
    const int lda = s0 ? lda0 : HID;
    const int kof = kk + kgrp * 8;
#pragma unroll
    for (int i = 0; i < 2; ++i) {
      const size_t aoff = (GATHER && s0)
                              ? ((size_t)tok[i] * lda + kof)
                              : ((size_t)arow[i] * lda + kof);
      const size_t woff = (size_t)wrow[i] * lda + kof;
      const int sbase = wid * 64 + i * 256;  // wave-uniform; +lane*16 by HW
      gl_lds16(ah + aoff, ldso(buf, 0, sbase));
      gl_lds16(al + aoff, ldso(buf, 1, sbase));
      gl_lds16(wh + woff, ldso(buf, 2, sbase));
      gl_lds16(wl + woff, ldso(buf, 3, sbase));
    }
  };

  f32x4 acc[4][4] = {};

  auto compute = [&](int buf) {
    half8 ah[4], al[4];
#pragma unroll
    for (int mi = 0; mi < 4; ++mi) {
      ah[mi] = *(const half8*)ldso(buf, 0, (wm * 4 + mi) * 64 + lane);
      al[mi] = *(const half8*)ldso(buf, 1, (wm * 4 + mi) * 64 + lane);
    }
#pragma unroll
    for (int ni = 0; ni < 4; ++ni) {
      const half8 bh = *(const half8*)ldso(buf, 2, (wn * 4 + ni) * 64 + lane);
      const half8 bl = *(const half8*)ldso(buf, 3, (wn * 4 + ni) * 64 + lane);
#pragma unroll
      for (int mi = 0; mi < 4; ++mi) {
        acc[mi][ni] =
            __builtin_amdgcn_mfma_f32_16x16x32_f16(ah[mi], bh, acc[mi][ni], 0, 0, 0);
        acc[mi][ni] =
            __builtin_amdgcn_mfma_f32_16x16x32_f16(ah[mi], bl, acc[mi][ni], 0, 0, 0);
        acc[mi][ni] =
            __builtin_amdgcn_mfma_f32_16x16x32_f16(al[mi], bh, acc[mi][ni], 0, 0, 0);
      }
    }
  };

  stage(0, 0);
  __syncthreads();  // drains vmcnt -> buf0 ready
#pragma unroll 1
  for (int t = 0; t < NT; ++t) {
    if (t + 1 < NT) stage((t + 1) & 1, t + 1);  // fly under compute(t)
    compute(t & 1);
    __syncthreads();  // drain t+1 loads + protect buf reuse
  }

  // ---- epilogue: exchange C through LDS, fp64 cell update ----
  float* cb = (float*)lds;  // [128][132]
#pragma unroll
  for (int mi = 0; mi < 4; ++mi)
#pragma unroll
    for (int ni = 0; ni < 4; ++ni) {
      const int col = wn * 64 + ni * 16 + (lane & 15);
      const int rb = wm * 64 + mi * 16 + ((lane >> 4) << 2);
#pragma unroll
      for (int r = 0; r < 4; ++r) cb[(rb + r) * 132 + col] = acc[mi][ni][r];
    }
  __syncthreads();

#pragma unroll 1
  for (int i = 0; i < 16; ++i) {
    const int idx = tid + i * 256;
    const int r = idx >> 5, ui = idx & 31;
    const int grow = row0 + r;
    const int u = u0 + ui;
    const float* cr = cb + r * 132 + ui;
    const double gI = (double)cr[0]  * INV_S2 + (double)bih[u]           + (double)bhh[u];
    const double gF = (double)cr[32] * INV_S2 + (double)bih[HID + u]     + (double)bhh[HID + u];
    const double gG = (double)cr[64] * INV_S2 + (double)bih[2 * HID + u] + (double)bhh[2 * HID + u];
    const double gO = (double)cr[96] * INV_S2 + (double)bih[3 * HID + u] + (double)bhh[3 * HID + u];
    const double ii = 1.0 / (1.0 + exp(-gI));
    const double ff = 1.0 / (1.0 + exp(-gF));
    const double gt = tanh(gG);
    const double oo = 1.0 / (1.0 + exp(-gO));
    const size_t off = (size_t)grow * HID + u;
    const double cn = ff * (double)Cst[off] + ii * gt;
    Cst[off] = (float)cn;
    const float hf = (float)(oo * tanh(cn));
    if (WRITE_F32) Hf32[off] = hf;
    const float hs = hf * SCALE;
    const _Float16 hh = (_Float16)hs;
    const float rem = hs - (float)hh;
    const _Float16 hl = (_Float16)rem;
    Hhi[off] = __builtin_bit_cast(u16, hh);
    Hlo[off] = __builtin_bit_cast(u16, hl);
  }
}

// ---------------------------------------------------------------------------
// Logits + gumbel + argmax + EOS bookkeeping (fp64, unchanged — proven).
// ---------------------------------------------------------------------------
__global__ __launch_bounds__(256) void sample_kernel(
    const float* __restrict__ h1, const float* __restrict__ Wout,
    const float* __restrict__ bout, const u32* __restrict__ keys, int t,
    int* __restrict__ prev, int* __restrict__ is_end, int* __restrict__ lengths,
    int* __restrict__ out_tok, int* __restrict__ len_out) {
  const int wave = threadIdx.x >> 6;
  const int lane = threadIdx.x & 63;
  const int row = blockIdx.x * 4 + wave;
  const int v = lane & 31;
  const int half = lane >> 5;

  const float* hseg = h1 + (size_t)row * HID + half * (HID / 2);
  const float* wseg = Wout + (size_t)v * HID + half * (HID / 2);

  double acc = 0.0;
#pragma unroll 4
  for (int k = 0; k < HID / 2; k += 4) {
    const float4 w = *(const float4*)(wseg + k);
    const float4 h = *(const float4*)(hseg + k);
    acc = fma((double)w.x, (double)h.x, acc);
    acc = fma((double)w.y, (double)h.y, acc);
    acc = fma((double)w.z, (double)h.z, acc);
    acc = fma((double)w.w, (double)h.w, acc);
  }
  acc += __shfl_xor(acc, 32);

  const u32 k0 = keys[2 * t], k1 = keys[2 * t + 1];
  u32 y0, y1;
  threefry2x32(k0, k1, 0u, (u32)(row * VOCAB + v), y0, y1);
  const u32 bits = y0 ^ y1;
  const float f = __uint_as_float((bits >> 9) | 0x3f800000u) - 1.0f;
  const float uu = fmaxf(f, 1.17549435e-38f);
  const double g = -log(-log((double)uu));

  double z = acc + (double)bout[v] + g;
  int idx = v;
#pragma unroll
  for (int m = 1; m < 32; m <<= 1) {
    const double zo = __shfl_xor(z, m);
    const int io = __shfl_xor(idx, m);
    if (zo > z || (zo == z && io < idx)) { z = zo; idx = io; }
  }

  if (lane == 0) {
    const int e = is_end[row];
    const int cur = e ? PAD_TOK : idx;
    const int len = lengths[row] + (e ? 0 : 1);
    const int enew = e | (cur == EOS_TOK ? 1 : 0);
    prev[row] = cur;
    is_end[row] = enew;
    lengths[row] = len;
    out_tok[(size_t)row * (MAXLEN + 1) + t + 1] = cur;
    if (len_out) len_out[row] = len + 1;
  }
}

// ---------------------------------------------------------------------------
extern "C" void kernel_launch(void* const* d_in, const int* in_sizes, int n_in,
                              void* d_out, int out_size, void* d_ws,
                              size_t ws_size, hipStream_t stream) {
  const int* prevs = (const int*)d_in[0];
  const float* emb = (const float*)d_in[1];
  const float* Wih0 = (const float*)d_in[2];
  const float* Whh0 = (const float*)d_in[3];
  const float* bih0 = (const float*)d_in[4];
  const float* bhh0 = (const float*)d_in[5];
  const float* Wih1 = (const float*)d_in[6];
  const float* Whh1 = (const float*)d_in[7];
  const float* bih1 = (const float*)d_in[8];
  const float* bhh1 = (const float*)d_in[9];
  const float* Wout = (const float*)d_in[10];
  const float* bout = (const float*)d_in[11];

  const size_t SH = (size_t)BATCH * HID;        // 2M elements
  const size_t SW = (size_t)(4 * HID) * HID;    // 4M elements
  const size_t SW0 = (size_t)(4 * HID) * EMB;   // 256K elements

  float* c0 = (float*)d_ws;
  float* c1 = c0 + SH;
  float* h1f = c1 + SH;
  u16* u = (u16*)(h1f + SH);
  u16* h0hi[2] = {u, u + SH};
  u16* h0lo[2] = {u + 2 * SH, u + 3 * SH};
  u16* h1hi[2] = {u + 4 * SH, u + 5 * SH};
  u16* h1lo[2] = {u + 6 * SH, u + 7 * SH};
  u16* wp = u + 8 * SH;
  u16* wih0hi = wp;            u16* wih0lo = wp + SW0;
  u16* whh0hi = wp + 2 * SW0;  u16* whh0lo = whh0hi + SW;
  u16* wih1hi = whh0lo + SW;   u16* wih1lo = wih1hi + SW;
  u16* whh1hi = wih1lo + SW;   u16* whh1lo = whh1hi + SW;
  u16* embhi = whh1lo + SW;    u16* emblo = embhi + VOCAB * EMB;
  int* prev = (int*)(emblo + VOCAB * EMB);
  int* is_end = prev + BATCH;
  int* lengths = is_end + BATCH;
  u32* keys = (u32*)(lengths + BATCH);
  // total ~106 MB

  int* out_tok = (int*)d_out;
  int* len_out = out_tok + (size_t)BATCH * (MAXLEN + 1);

  init_kernel<<<dim3((BATCH * HID) / 256), 256, 0, stream>>>(
      prevs, c0, c1, h0hi[0], h0lo[0], h0hi[1], h0lo[1], h1hi[0], h1lo[0],
      h1hi[1], h1lo[1], prev, is_end, lengths, keys, out_tok);

  split_kernel<<<dim3((int)((SW0 + 255) / 256)), 256, 0, stream>>>(Wih0, wih0hi, wih0lo, (int)SW0);
  split_kernel<<<dim3((int)((SW + 255) / 256)), 256, 0, stream>>>(Whh0, whh0hi, whh0lo, (int)SW);
  split_kernel<<<dim3((int)((SW + 255) / 256)), 256, 0, stream>>>(Wih1, wih1hi, wih1lo, (int)SW);
  split_kernel<<<dim3((int)((SW + 255) / 256)), 256, 0, stream>>>(Whh1, whh1hi, whh1lo, (int)SW);
  split_kernel<<<dim3((VOCAB * EMB + 255) / 256), 256, 0, stream>>>(emb, embhi, emblo, VOCAB * EMB);

  int p = 0;
  for (int t = 0; t < MAXLEN; ++t) {
    lstm_mfma<true, false><<<dim3(512), 256, 0, stream>>>(
        embhi, emblo, EMB, EMB / BK, prev, h0hi[p], h0lo[p], wih0hi, wih0lo,
        whh0hi, whh0lo, bih0, bhh0, c0, nullptr, h0hi[p ^ 1], h0lo[p ^ 1]);
    lstm_mfma<false, true><<<dim3(512), 256, 0, stream>>>(
        h0hi[p ^ 1], h0lo[p ^ 1], HID, HID / BK, nullptr, h1hi[p], h1lo[p],
        wih1hi, wih1lo, whh1hi, whh1lo, bih1, bhh1, c1, h1f, h1hi[p ^ 1],
        h1lo[p ^ 1]);
    sample_kernel<<<dim3(BATCH / 4), 256, 0, stream>>>(
        h1f, Wout, bout, keys, t, prev, is_end, lengths, out_tok,
        (t == MAXLEN - 1) ? len_out : nullptr);
    p ^= 1;
  }
  (void)in_sizes; (void)n_in; (void)out_size; (void)ws_size;
}